// Round 9
// baseline (205.986 us; speedup 1.0000x reference)
//
#include <hip/hip_runtime.h>
#include <hip/hip_fp16.h>
#include <math.h>

// hybridDynamicSimNew: B=65536 cars, H=5, F=50. R9 = R8 (MFMA) + spill fix.
//
// R8 post-mortem: VGPR_Count=60 -- __launch_bounds__(256) without min-waves
// let the allocator target the default 8-waves/EU budget (64 VGPRs) and
// spill ALL persistent state (window uints, A-frags, C-frags) to scratch;
// per-sub-step scratch reloads at ~L2 latency = the ~3700cy/sub-step stall
// (VALUBusy 30%, MfmaUtil 8%, both pipes waiting). FETCH unchanged at 23.5MB
// = scratch stayed L2-resident (invisible to HBM counters).
// Fixes:
//  1. __launch_bounds__(256, 1): budget back to >=256 regs (live set ~150).
//  2. LDS writes+reads fused at sub-step top (same-wave DS is in-order);
//     physics VALU (~200cy) now covers the LDS round-trip latency.
//  3. fc1/fc2 hi/lo accumulator chains split (dep depth 4->2) + final adds.
// MFMA structure, layouts, and numerics identical to the passing R8
// (absmax 0.0726).

typedef _Float16 h4_t __attribute__((ext_vector_type(4)));
typedef float f32x4 __attribute__((ext_vector_type(4)));

__device__ __forceinline__ float rfl(float x) {
    return __int_as_float(__builtin_amdgcn_readfirstlane(__float_as_int(x)));
}
__device__ __forceinline__ unsigned int cvt16(float v) {  // f32->f16 RTN, zext
    return (unsigned int)__half_as_ushort(__float2half(v));
}
__device__ __forceinline__ unsigned int pk_f16(float a, float b) {
    return cvt16(a) | (cvt16(b) << 16);
}
__device__ __forceinline__ h4_t mk_h4(unsigned int a, unsigned int b) {
    union { unsigned int u[2]; h4_t h; } v;
    v.u[0] = a; v.u[1] = b; return v.h;
}
__device__ __forceinline__ f32x4 mfma16(h4_t a, h4_t b, f32x4 c) {
    return __builtin_amdgcn_mfma_f32_16x16x16f16(a, b, c, 0, 0, 0);
}
__device__ __forceinline__ void split16(float v, unsigned int& hi,
                                        unsigned int& lo) {
    unsigned int h = cvt16(v);
    float hf = __half2float(__ushort_as_half((unsigned short)h));
    lo = cvt16(v - hf);
    hi = h;
}

__device__ __forceinline__ float fast_tanhf(float x) {
    float e = __builtin_amdgcn_exp2f(x * 2.8853900817779268f);
    return 1.0f - 2.0f * __builtin_amdgcn_rcpf(e + 1.0f);
}
// sin(x) for |x| <= ~0.16 (tire model: |tC*atan| <= 0.1*pi/2)
__device__ __forceinline__ float sin_small(float x) {
    float x2 = x * x;
    return x * (1.0f + x2 * (-1.66666667e-1f + x2 * 8.33333338e-3f));
}
// branchless full-range atan, max err ~1.5e-6 rad
__device__ __forceinline__ float fatanf(float x) {
    float ax = fabsf(x);
    bool big = ax > 1.0f;
    float z  = big ? __builtin_amdgcn_rcpf(ax) : ax;
    float z2 = z * z;
    float p = fmaf(z2, -0.0117212f, 0.05265332f);
    p = fmaf(z2, p, -0.11643287f);
    p = fmaf(z2, p,  0.19354346f);
    p = fmaf(z2, p, -0.33262347f);
    p = fmaf(z2, p,  0.99997726f);
    float r = z * p;
    r = big ? (1.57079632679489662f - r) : r;
    return copysignf(r, x);
}

// W1 element in the padded k-domain: k = cat*6 + t (t=0..4 data, t=5 pad).
__device__ __forceinline__ float w1_elem(const float* w1, int o, int k) {
    int cat = k / 6;
    int t = k - 6 * cat;
    return (t < 5 && k < 30) ? w1[o * 25 + cat * 5 + t] : 0.0f;
}

__global__ __launch_bounds__(256, 1)
void sim_kernel(const float* __restrict__ fs,   // (B,5,8)
                const float* __restrict__ act,  // (B,50,2)
                const float* __restrict__ w1,   // (16,25) [o][k]
                const float* __restrict__ b1,   // (16)
                const float* __restrict__ w2,   // (3,16)
                const float* __restrict__ b2,   // (3)
                const float* __restrict__ prm,  // (10)
                const int*   __restrict__ rnnp, // (1)
                float* __restrict__ out)        // (B,50,8)
{
    // 4 waves x 64 rows x 32 uints (128B rows; slack enables the
    // (lane&7)<<2 XOR swizzle for conflict-light b128/b64).
    __shared__ unsigned int sF[8192];

    const int tid  = threadIdx.x;
    const int lane = tid & 63;
    const int wid  = tid >> 6;
    const int gg   = lane >> 4;   // k-block group (0..3)
    const int mm   = lane & 15;   // row/col within 16-tile
    unsigned int* wbase = &sF[wid * 2048];

    const int swz = (lane & 7) << 2;  // XOR swizzle in uint units (16B blocks)

    unsigned int* wp0 = &wbase[lane * 32 + (0  ^ swz)];
    unsigned int* wp1 = &wbase[lane * 32 + (4  ^ swz)];
    unsigned int* wp2 = &wbase[lane * 32 + (8  ^ swz)];
    unsigned int* wp3 = &wbase[lane * 32 + (12 ^ swz)];
#define DECL_RP(Q, H) \
    const uint2* rp##Q##H = (const uint2*)&wbase[(16 * (Q) + mm) * 32 + \
                                                 ((2 * gg + 8 * (H)) ^ swz)];
    DECL_RP(0,0) DECL_RP(0,1) DECL_RP(1,0) DECL_RP(1,1)
    DECL_RP(2,0) DECL_RP(2,1) DECL_RP(3,0) DECL_RP(3,1)
#undef DECL_RP

    const int car = blockIdx.x * 256 + tid;

    const float4* fsp = reinterpret_cast<const float4*>(fs + (size_t)car * 40);
    const float4* ap  = reinterpret_cast<const float4*>(act + (size_t)car * 100);
    float4 acur = ap[0];

    float wf[40];
#pragma unroll
    for (int i = 0; i < 10; ++i) {
        float4 v = fsp[i];
        wf[i * 4 + 0] = v.x; wf[i * 4 + 1] = v.y;
        wf[i * 4 + 2] = v.z; wf[i * 4 + 3] = v.w;
    }

    // wave-uniform physics params -> SGPR
    const float lf = rfl(prm[0]), lr = rfl(prm[1]), mIz = rfl(prm[2]);
    const float cm1 = rfl(prm[3]), cm2 = rfl(prm[4]), cr = rfl(prm[5]);
    const float cd = rfl(prm[6]);
    const float tB = rfl(prm[7]), tC = rfl(prm[8]), tD = rfl(prm[9]);
    const int   rnn = __builtin_amdgcn_readfirstlane(rnnp[0]);
    const float dt = 0.01f;
    const float PI = 3.14159265358979323846f;
    const float INV2PI = 0.15915494309189535f;
    const float TWOPI = 6.28318530717958647692f;

    // ---- A-fragments (prologue-only) ----
    h4_t a1h0, a1l0, a1h1, a1l1;
    {
        unsigned int h[8], l[8];
#pragma unroll
        for (int j = 0; j < 4; ++j) split16(w1_elem(w1, mm, 4 * gg + j), h[j], l[j]);
#pragma unroll
        for (int j = 0; j < 4; ++j) split16(w1_elem(w1, mm, 16 + 4 * gg + j), h[4 + j], l[4 + j]);
        a1h0 = mk_h4(h[0] | (h[1] << 16), h[2] | (h[3] << 16));
        a1l0 = mk_h4(l[0] | (l[1] << 16), l[2] | (l[3] << 16));
        a1h1 = mk_h4(h[4] | (h[5] << 16), h[6] | (h[7] << 16));
        a1l1 = mk_h4(l[4] | (l[5] << 16), l[6] | (l[7] << 16));
    }
    h4_t a2h, a2l;
    {
        unsigned int h[4], l[4];
#pragma unroll
        for (int j = 0; j < 4; ++j) {
            float v = (mm < 3) ? w2[mm * 16 + 4 * gg + j] : 0.0f;
            split16(v, h[j], l[j]);
        }
        a2h = mk_h4(h[0] | (h[1] << 16), h[2] | (h[3] << 16));
        a2l = mk_h4(l[0] | (l[1] << 16), l[2] | (l[3] << 16));
    }
    f32x4 c1;
    {
        float4 v = *reinterpret_cast<const float4*>(b1 + 4 * gg);
        c1[0] = v.x; c1[1] = v.y; c1[2] = v.z; c1[3] = v.w;
    }
    f32x4 c2;
    {
        float bz0 = b2[0], bz1 = b2[1], bz2 = b2[2];
        bool v = (lane < 16);
        c2[0] = v ? bz0 : 0.0f;
        c2[1] = v ? bz1 : 0.0f;
        c2[2] = v ? bz2 : 0.0f;
        c2[3] = 0.0f;
    }
    const f32x4 zero4 = {0.0f, 0.0f, 0.0f, 0.0f};

    // ---- initial feature window: 15 packed-f16 uints ----
    float vxh[5], vyh[5];
#pragma unroll
    for (int t = 0; t < 5; ++t) {
        float ph = wf[t * 8 + 4];
        float ch = __cosf(ph), sh = __sinf(ph);
        vxh[t] =  wf[t * 8 + 1] * ch + wf[t * 8 + 3] * sh;
        vyh[t] = -wf[t * 8 + 1] * sh + wf[t * 8 + 3] * ch;
    }
    unsigned int wu0_0 = pk_f16(vxh[0], vxh[1]);
    unsigned int wu0_1 = pk_f16(vxh[2], vxh[3]);
    unsigned int wu0_2 = cvt16(vxh[4]);
    unsigned int wu1_0 = pk_f16(vyh[0], vyh[1]);
    unsigned int wu1_1 = pk_f16(vyh[2], vyh[3]);
    unsigned int wu1_2 = cvt16(vyh[4]);
    unsigned int wu2_0 = pk_f16(wf[5],  wf[13]);
    unsigned int wu2_1 = pk_f16(wf[21], wf[29]);
    unsigned int wu2_2 = cvt16(wf[37]);
    unsigned int wu3_0 = pk_f16(wf[6],  wf[14]);
    unsigned int wu3_1 = pk_f16(wf[22], wf[30]);
    unsigned int wu3_2 = cvt16(wf[38]);
    unsigned int wu4_0 = pk_f16(wf[7],  wf[15]);
    unsigned int wu4_1 = pk_f16(wf[23], wf[31]);
    unsigned int wu4_2 = cvt16(wf[39]);

    float x = wf[32], y = wf[34], psi = wf[36];
    float c = __cosf(psi), s = __sinf(psi);
    float Vxc = vxh[4], Vyc = vyh[4];
    float thr_c = wf[38], str_c = wf[39];

    float* outp = out + (size_t)car * 400;

#pragma unroll 1
    for (int f2 = 0; f2 < 25; ++f2) {
        float4 anext = ap[(f2 < 24) ? (f2 + 1) : 24];

#pragma unroll
        for (int sub = 0; sub < 2; ++sub) {
            const float a0 = sub ? acur.z : acur.x;
            const float a1 = sub ? acur.w : acur.y;

            // ---- stage + read-back FIRST (same-wave DS is in-order);
            //      the physics VALU below covers the LDS latency. ----
            uint2 b00, b01, b10, b11, b20, b21, b30, b31;
            if (rnn) {
                *reinterpret_cast<uint4*>(wp0) = make_uint4(wu0_0, wu0_1, wu0_2, wu1_0);
                *reinterpret_cast<uint4*>(wp1) = make_uint4(wu1_1, wu1_2, wu2_0, wu2_1);
                *reinterpret_cast<uint4*>(wp2) = make_uint4(wu2_2, wu3_0, wu3_1, wu3_2);
                *reinterpret_cast<uint4*>(wp3) = make_uint4(wu4_0, wu4_1, wu4_2, 0u);
                b00 = *rp00; b01 = *rp01; b10 = *rp10; b11 = *rp11;
                b20 = *rp20; b21 = *rp21; b30 = *rp30; b31 = *rp31;
            }

            // ---- physics (f32), overlaps the LDS round-trip ----
            const float atr    = fatanf(Vyc * __builtin_amdgcn_rcpf(Vxc));
            const float slip_f = -atr + str_c;
            const float slip_r = -atr;
            const float laf = tD * sin_small(tC * fatanf(tB * slip_f));
            const float lar = tD * sin_small(tC * fatanf(tB * slip_r));
            const float st_s = __sinf(str_c), st_c = __cosf(str_c);
            const float fwd  = (cm1 - cm2 * Vxc) * thr_c - cr - cd * Vxc * Vxc;

            float Vx2   = Vxc + (fwd - laf * st_s) * dt;
            float Vy2   = Vyc + (lar + laf * st_c) * dt;
            float omega = mIz * (laf * lf * st_c - lar * lr) * dt;

            if (rnn) {
                // ---- fc1: 16 MFMAs, hi/lo chains split (depth 4 -> 2) ----
                f32x4 dh0 = c1, dh1 = c1, dh2 = c1, dh3 = c1;
                f32x4 dl0 = zero4, dl1 = zero4, dl2 = zero4, dl3 = zero4;
#define FC1(DH, DL, BL, BH)                                   \
                DH = mfma16(a1h0, mk_h4(BL.x, BL.y), DH);     \
                DL = mfma16(a1l0, mk_h4(BL.x, BL.y), DL);     \
                DH = mfma16(a1h1, mk_h4(BH.x, BH.y), DH);     \
                DL = mfma16(a1l1, mk_h4(BH.x, BH.y), DL);
                FC1(dh0, dl0, b00, b01) FC1(dh1, dl1, b10, b11)
                FC1(dh2, dl2, b20, b21) FC1(dh3, dl3, b30, b31)
#undef FC1
                f32x4 d0 = dh0 + dl0, d1 = dh1 + dl1;
                f32x4 d2 = dh2 + dl2, d3 = dh3 + dl3;

                // ---- tanh + pack: D-frag -> B-frag of fc2 ----
                h4_t th0 = mk_h4(pk_f16(fast_tanhf(d0[0]), fast_tanhf(d0[1])),
                                 pk_f16(fast_tanhf(d0[2]), fast_tanhf(d0[3])));
                h4_t th1 = mk_h4(pk_f16(fast_tanhf(d1[0]), fast_tanhf(d1[1])),
                                 pk_f16(fast_tanhf(d1[2]), fast_tanhf(d1[3])));
                h4_t th2 = mk_h4(pk_f16(fast_tanhf(d2[0]), fast_tanhf(d2[1])),
                                 pk_f16(fast_tanhf(d2[2]), fast_tanhf(d2[3])));
                h4_t th3 = mk_h4(pk_f16(fast_tanhf(d3[0]), fast_tanhf(d3[1])),
                                 pk_f16(fast_tanhf(d3[2]), fast_tanhf(d3[3])));

                // ---- fc2: 8 MFMAs, hi/lo split (depth 2 -> 1) ----
                f32x4 e0 = mfma16(a2h, th0, c2) + mfma16(a2l, th0, zero4);
                f32x4 e1 = mfma16(a2h, th1, c2) + mfma16(a2l, th1, zero4);
                f32x4 e2 = mfma16(a2h, th2, c2) + mfma16(a2l, th2, zero4);
                f32x4 e3 = mfma16(a2h, th3, c2) + mfma16(a2l, th3, zero4);

                // ---- broadcast z from lane mm, select own frag q=gg ----
                float q0z0 = __shfl(e0[0], mm, 64), q0z1 = __shfl(e0[1], mm, 64), q0z2 = __shfl(e0[2], mm, 64);
                float q1z0 = __shfl(e1[0], mm, 64), q1z1 = __shfl(e1[1], mm, 64), q1z2 = __shfl(e1[2], mm, 64);
                float q2z0 = __shfl(e2[0], mm, 64), q2z1 = __shfl(e2[1], mm, 64), q2z2 = __shfl(e2[2], mm, 64);
                float q3z0 = __shfl(e3[0], mm, 64), q3z1 = __shfl(e3[1], mm, 64), q3z2 = __shfl(e3[2], mm, 64);
                bool s1 = (lane & 16) != 0, s2 = (lane & 32) != 0;
                float z0 = s2 ? (s1 ? q3z0 : q2z0) : (s1 ? q1z0 : q0z0);
                float z1 = s2 ? (s1 ? q3z1 : q2z1) : (s1 ? q1z1 : q0z1);
                float z2 = s2 ? (s1 ? q3z2 : q2z2) : (s1 ? q1z2 : q0z2);

                Vx2   += fast_tanhf(z0) * 5.0f * dt;
                Vy2   += fast_tanhf(z1) * 5.0f * dt;
                omega += fast_tanhf(z2) * 3.0f * dt;
            }

            // ---- global-frame update ----
            const float Vxg = Vx2 * c - Vy2 * s;
            const float Vyg = Vx2 * s + Vy2 * c;
            float pn = psi + omega * dt + PI;
            pn = pn - floorf(pn * INV2PI) * TWOPI - PI;

            x = x + Vxg * dt;
            y = y + Vyg * dt;

            float4 o0 = make_float4(x, Vxg, y, Vyg);
            float4 o1 = make_float4(pn, omega, a0, a1);
            reinterpret_cast<float4*>(outp)[0] = o0;
            reinterpret_cast<float4*>(outp)[1] = o1;
            outp += 8;

            // ---- advance state, shift window (alignbit), insert new ----
            psi = pn;
            c = __cosf(pn);
            s = __sinf(pn);
            float nVx =  Vxg * c + Vyg * s;
            float nVy = -Vxg * s + Vyg * c;
#define SHIFTCAT(C, NEWV)                                              \
            wu##C##_0 = __builtin_amdgcn_alignbit(wu##C##_1, wu##C##_0, 16); \
            wu##C##_1 = __builtin_amdgcn_alignbit(wu##C##_2, wu##C##_1, 16); \
            wu##C##_2 = cvt16(NEWV);
            SHIFTCAT(0, nVx) SHIFTCAT(1, nVy) SHIFTCAT(2, omega)
            SHIFTCAT(3, a0)  SHIFTCAT(4, a1)
#undef SHIFTCAT
            Vxc = nVx; Vyc = nVy; thr_c = a0; str_c = a1;
        }
        acur = anext;
    }
}

extern "C" void kernel_launch(void* const* d_in, const int* in_sizes, int n_in,
                              void* d_out, int out_size, void* d_ws, size_t ws_size,
                              hipStream_t stream) {
    const float* fs  = (const float*)d_in[0];
    const float* act = (const float*)d_in[1];
    const float* w1  = (const float*)d_in[2];
    const float* b1  = (const float*)d_in[3];
    const float* w2  = (const float*)d_in[4];
    const float* b2  = (const float*)d_in[5];
    const float* prm = (const float*)d_in[6];
    const int*   rnn = (const int*)d_in[7];
    float* out = (float*)d_out;

    const int Bn = in_sizes[0] / 40;  // 65536 cars, 1 thread each
    dim3 grid(Bn / 256), block(256);
    hipLaunchKernelGGL(sim_kernel, grid, block, 0, stream,
                       fs, act, w1, b1, w2, b2, prm, rnn, out);
}